// Round 1
// 209.872 us; speedup vs baseline: 1.0844x; 1.0844x over previous
//
#include <hip/hip_runtime.h>

typedef short short8 __attribute__((ext_vector_type(8)));
typedef int   intx8  __attribute__((ext_vector_type(8)));
typedef float floatx16 __attribute__((ext_vector_type(16)));

__device__ __forceinline__ unsigned pk4(int a, int b, int c, int d) {
    return (a & 255) | ((b & 255) << 8) | ((c & 255) << 16) | ((unsigned)(d & 255) << 24);
}

// E4M3 code + E8M0 scale exponent (esf = sf-127) -> bf16 bits. Exact, integer-only.
// NaN code (e=15,m=7) decodes to 480*2^esf like the reference (this is why fp8
// cannot use the HW f8f6f4 path: HW would produce NaN).
__device__ __forceinline__ unsigned dec8bf(int c, int esf) {
    int s = (c & 128) << 8;
    int e = (c >> 3) & 15, m = c & 7;
    int rn = s | ((e + 120 + esf) << 7) | (m << 4);                 // normal: (1+m/8)*2^(e-7)
    int nb = (m >= 4) ? 2 : ((m >= 2) ? 1 : 0);                     // floor(log2 m)
    int rs = m ? (s | ((nb + 118 + esf) << 7) | ((m << (7 - nb)) & 0x7F)) : s;  // subnormal m*2^-9
    return (unsigned)(e ? rn : rs);
}

// ---- prepass (per side): k-major repack so GEMM fragment loads are coalesced.
// C4 [96][R][16]  : fp4 codes, 16B chunk j = k nibbles 32j..32j+31
// C6 [24][R][24]  : fp6 raw 6-bit stream, 24B window g = k 32g..32g+31
// C8 [32][R][8]   : fp8 decoded+scaled to bf16, 16B chunk j = k 8j..8j+7
// St [36][R][4]   : rows 0..23 fp4 scale quads (byte i = block 4q+i); rows 24..35 fp6 pairs
// Thread mapping reworked so fp4/fp8 threads each consume one full 128B line.
__device__ __forceinline__ void pack_one(
    int t, const int* __restrict__ Pn, const int* __restrict__ Ps, const int* __restrict__ Po,
    const int* __restrict__ Sn, const int* __restrict__ Ss, const int* __restrict__ So,
    unsigned char* __restrict__ C4, unsigned char* __restrict__ C6,
    unsigned short* __restrict__ C8, unsigned char* __restrict__ St, int R)
{
    int T0 = R * 48, T1 = T0 + R * 24, T2 = T1 + R * 8, T3 = T2 + R * 24, T4 = T3 + R * 12;
    if (t < T0) {                                  // fp4: 128B line -> 2 chunks of 16B
        int jj = t / R, r = t - jj * R;
        const int4* p = (const int4*)(Pn + (size_t)r * 1536 + jj * 32);
        #pragma unroll
        for (int h = 0; h < 2; ++h) {
            uint4 o; unsigned* po = (unsigned*)&o;
            #pragma unroll
            for (int q = 0; q < 4; q++) { int4 b = p[4 * h + q]; po[q] = pk4(b.x, b.y, b.z, b.w); }
            *(uint4*)(C4 + ((size_t)(2 * jj + h) * R + r) * 16) = o;
        }
    } else if (t < T1) {                           // fp6: 24 B window from 24 int32
        t -= T0; int g = t / R, r = t - g * R;
        const int4* p = (const int4*)(Ps + (size_t)r * 576 + g * 24);
        unsigned d[6];
        #pragma unroll
        for (int q = 0; q < 6; q++) { int4 b = p[q]; d[q] = pk4(b.x, b.y, b.z, b.w); }
        unsigned char* dst = C6 + ((size_t)g * R + r) * 24;
        *(int2*)(dst)      = (int2){ (int)d[0], (int)d[1] };
        *(int2*)(dst + 8)  = (int2){ (int)d[2], (int)d[3] };
        *(int2*)(dst + 16) = (int2){ (int)d[4], (int)d[5] };
    } else if (t < T2) {                           // fp8: 128B line -> 32 scaled bf16 (4 chunks)
        t -= T1; int jj = t / R, r = t - jj * R;
        const int4* p = (const int4*)(Po + (size_t)r * 256 + jj * 32);
        int e = So[r * 8 + jj] - 127;              // 32 codes = exactly one scale block
        #pragma unroll
        for (int cq = 0; cq < 4; ++cq) {
            int4 c0 = p[2 * cq], c1 = p[2 * cq + 1];
            int cs[8] = { c0.x, c0.y, c0.z, c0.w, c1.x, c1.y, c1.z, c1.w };
            uint4 o; unsigned* po = (unsigned*)&o;
            #pragma unroll
            for (int i = 0; i < 4; i++)
                po[i] = dec8bf(cs[2 * i] & 255, e) | (dec8bf(cs[2 * i + 1] & 255, e) << 16);
            *(uint4*)((unsigned char*)C8 + ((size_t)(4 * jj + cq) * R + r) * 16) = o;
        }
    } else if (t < T3) {                           // fp4 scale quads
        t -= T2; int q = t / R, r = t - q * R;
        int4 v = *(const int4*)(Sn + (size_t)r * 96 + q * 4);
        *(unsigned*)(St + ((size_t)q * R + r) * 4) = pk4(v.x, v.y, v.z, v.w);
    } else if (t < T4) {                           // fp6 scale pairs
        t -= T3; int b2 = t / R, r = t - b2 * R;
        int s0 = Ss[(size_t)r * 24 + 2 * b2] & 255, s1 = Ss[(size_t)r * 24 + 2 * b2 + 1] & 255;
        *(unsigned*)(St + ((size_t)(24 + b2) * R + r) * 4) = (unsigned)(s0 | (s1 << 8));
    }
}

__global__ __launch_bounds__(256) void pack_both(
    const int* __restrict__ AN, const int* __restrict__ AS, const int* __restrict__ AO,
    const int* __restrict__ SAn, const int* __restrict__ SAs, const int* __restrict__ SAo,
    unsigned char* __restrict__ A4, unsigned char* __restrict__ A6,
    unsigned short* __restrict__ A8, unsigned char* __restrict__ SaT, int M,
    const int* __restrict__ BN, const int* __restrict__ BS, const int* __restrict__ BO,
    const int* __restrict__ SBn, const int* __restrict__ SBs, const int* __restrict__ SBo,
    unsigned char* __restrict__ B4, unsigned char* __restrict__ B6,
    unsigned short* __restrict__ B8, unsigned char* __restrict__ SbT, int N)
{
    int t = blockIdx.x * 256 + threadIdx.x;
    int TA = M * 116;
    if (t < TA) pack_one(t, AN, AS, AO, SAn, SAs, SAo, A4, A6, A8, SaT, M);
    else        pack_one(t - TA, BN, BS, BO, SBn, SBs, SBo, B4, B6, B8, SbT, N);
}

// ---- barrier-free direct-load MX GEMM with explicit software pipelining.
// 128x128 block, 4 waves, 2x2 of 32x32 acc/wave. fp4: depth-4 rotating register
// prefetch (16 fragment loads in flight/wave) + depth-2 scale-word pipeline;
// fp6/fp8: depth-2. Running 32-bit offsets keep address VALU at 1 add/ptr/step.
// Tail prefetch overruns are bounded stray reads into the adjacent workspace
// region (A4->B4, B4->A6, A8->B8, B8->SaT; SaT/SbT strays stay inside rows<36),
// except fp6 whose tail (v=10,11) is peeled since its scale rows end at the
// SbT region boundary.
__global__ __launch_bounds__(256, 2) void gemm_mx(
    const unsigned char* __restrict__ A4, const unsigned char* __restrict__ B4,
    const unsigned char* __restrict__ A6, const unsigned char* __restrict__ B6,
    const unsigned short* __restrict__ A8, const unsigned short* __restrict__ B8,
    const unsigned char* __restrict__ SaT, const unsigned char* __restrict__ SbT,
    const float* __restrict__ bias, float* __restrict__ C, int M, int N)
{
    int tid = threadIdx.x, w = tid >> 6, l = tid & 63;
    int bm = blockIdx.y, bn = blockIdx.x;
    int wm = (w >> 1) * 64, wn = (w & 1) * 64;
    int lr = l & 31, lh = l >> 5;

    floatx16 acc[2][2] = {};

    int rA[2] = { bm * 128 + wm + lr, bm * 128 + wm + 32 + lr };
    int cB[2] = { bn * 128 + wn + lr, bn * 128 + wn + 32 + lr };

    // ================= fp4 (fmt 4): 48 steps of K=64, depth-4 pipeline =================
    {
        unsigned strA = 32u * (unsigned)M, strB = 32u * (unsigned)N;
        unsigned fA0 = ((unsigned)lh * M + (unsigned)rA[0]) * 16u;
        unsigned fA1 = ((unsigned)lh * M + (unsigned)rA[1]) * 16u;
        unsigned fB0 = ((unsigned)lh * N + (unsigned)cB[0]) * 16u;
        unsigned fB1 = ((unsigned)lh * N + (unsigned)cB[1]) * 16u;

        int4 pa[4][2], pb[4][2];
        #pragma unroll
        for (int s = 0; s < 4; ++s) {
            pa[s][0] = *(const int4*)(A4 + fA0); pa[s][1] = *(const int4*)(A4 + fA1);
            pb[s][0] = *(const int4*)(B4 + fB0); pb[s][1] = *(const int4*)(B4 + fB1);
            fA0 += strA; fA1 += strA; fB0 += strB; fB1 += strB;
        }

        unsigned sstrA = 4u * (unsigned)M, sstrB = 4u * (unsigned)N;
        unsigned sA0 = (unsigned)rA[0] * 4u, sA1 = (unsigned)rA[1] * 4u;
        unsigned sB0 = (unsigned)cB[0] * 4u, sB1 = (unsigned)cB[1] * 4u;
        unsigned psa[2][2], psb[2][2];
        psa[0][0] = *(const unsigned*)(SaT + sA0);         psa[0][1] = *(const unsigned*)(SaT + sA1);
        psb[0][0] = *(const unsigned*)(SbT + sB0);         psb[0][1] = *(const unsigned*)(SbT + sB1);
        psa[1][0] = *(const unsigned*)(SaT + sA0 + sstrA); psa[1][1] = *(const unsigned*)(SaT + sA1 + sstrA);
        psb[1][0] = *(const unsigned*)(SbT + sB0 + sstrB); psb[1][1] = *(const unsigned*)(SbT + sB1 + sstrB);
        sA0 += 2 * sstrA; sA1 += 2 * sstrA; sB0 += 2 * sstrB; sB1 += 2 * sstrB;  // next: up=2

        #pragma unroll 4
        for (int u = 0; u < 48; ++u) {
            int sl = u & 3, wsl = (u >> 1) & 1;
            int sh = 8 * ((u & 1) * 2 + lh);
            int sa0 = (int)((psa[wsl][0] >> sh) & 255), sa1 = (int)((psa[wsl][1] >> sh) & 255);
            int sb0 = (int)((psb[wsl][0] >> sh) & 255), sb1 = (int)((psb[wsl][1] >> sh) & 255);
            intx8 A0 = (intx8){ pa[sl][0].x, pa[sl][0].y, pa[sl][0].z, pa[sl][0].w, 0, 0, 0, 0 };
            intx8 A1 = (intx8){ pa[sl][1].x, pa[sl][1].y, pa[sl][1].z, pa[sl][1].w, 0, 0, 0, 0 };
            intx8 B0 = (intx8){ pb[sl][0].x, pb[sl][0].y, pb[sl][0].z, pb[sl][0].w, 0, 0, 0, 0 };
            intx8 B1 = (intx8){ pb[sl][1].x, pb[sl][1].y, pb[sl][1].z, pb[sl][1].w, 0, 0, 0, 0 };
            acc[0][0] = __builtin_amdgcn_mfma_scale_f32_32x32x64_f8f6f4(A0, B0, acc[0][0], 4, 4, 0, sa0, 0, sb0);
            acc[0][1] = __builtin_amdgcn_mfma_scale_f32_32x32x64_f8f6f4(A0, B1, acc[0][1], 4, 4, 0, sa0, 0, sb1);
            acc[1][0] = __builtin_amdgcn_mfma_scale_f32_32x32x64_f8f6f4(A1, B0, acc[1][0], 4, 4, 0, sa1, 0, sb0);
            acc[1][1] = __builtin_amdgcn_mfma_scale_f32_32x32x64_f8f6f4(A1, B1, acc[1][1], 4, 4, 0, sa1, 0, sb1);
            // prefetch step u+4 into the slot just consumed (stray reads past the
            // section end land in the next workspace region; values never used)
            pa[sl][0] = *(const int4*)(A4 + fA0); pa[sl][1] = *(const int4*)(A4 + fA1);
            pb[sl][0] = *(const int4*)(B4 + fB0); pb[sl][1] = *(const int4*)(B4 + fB1);
            fA0 += strA; fA1 += strA; fB0 += strB; fB1 += strB;
            if (u & 1) {   // after second consume of this scale word, fetch up+2 (3 steps ahead)
                psa[wsl][0] = *(const unsigned*)(SaT + sA0); psa[wsl][1] = *(const unsigned*)(SaT + sA1);
                psb[wsl][0] = *(const unsigned*)(SbT + sB0); psb[wsl][1] = *(const unsigned*)(SbT + sB1);
                sA0 += sstrA; sA1 += sstrA; sB0 += sstrB; sB1 += sstrB;
            }
        }
    }

    // ================= fp6 (fmt 3): 12 steps of K=64, depth-2 pipeline =================
    {
        unsigned str6A = 48u * (unsigned)M, str6B = 48u * (unsigned)N;
        unsigned gA0 = ((unsigned)lh * M + (unsigned)rA[0]) * 24u;
        unsigned gA1 = ((unsigned)lh * M + (unsigned)rA[1]) * 24u;
        unsigned gB0 = ((unsigned)lh * N + (unsigned)cB[0]) * 24u;
        unsigned gB1 = ((unsigned)lh * N + (unsigned)cB[1]) * 24u;
        unsigned ss4A = 4u * (unsigned)M, ss4B = 4u * (unsigned)N;
        unsigned zA0 = (24u * (unsigned)M + (unsigned)rA[0]) * 4u;
        unsigned zA1 = (24u * (unsigned)M + (unsigned)rA[1]) * 4u;
        unsigned zB0 = (24u * (unsigned)N + (unsigned)cB[0]) * 4u;
        unsigned zB1 = (24u * (unsigned)N + (unsigned)cB[1]) * 4u;

        int2 qa[2][2][3], qb[2][2][3];
        unsigned p6a[2][2], p6b[2][2];
        #pragma unroll
        for (int s = 0; s < 2; ++s) {
            const unsigned char *a0 = A6 + gA0, *a1 = A6 + gA1, *b0 = B6 + gB0, *b1 = B6 + gB1;
            qa[s][0][0] = *(const int2*)(a0); qa[s][0][1] = *(const int2*)(a0 + 8); qa[s][0][2] = *(const int2*)(a0 + 16);
            qa[s][1][0] = *(const int2*)(a1); qa[s][1][1] = *(const int2*)(a1 + 8); qa[s][1][2] = *(const int2*)(a1 + 16);
            qb[s][0][0] = *(const int2*)(b0); qb[s][0][1] = *(const int2*)(b0 + 8); qb[s][0][2] = *(const int2*)(b0 + 16);
            qb[s][1][0] = *(const int2*)(b1); qb[s][1][1] = *(const int2*)(b1 + 8); qb[s][1][2] = *(const int2*)(b1 + 16);
            p6a[s][0] = *(const unsigned*)(SaT + zA0); p6a[s][1] = *(const unsigned*)(SaT + zA1);
            p6b[s][0] = *(const unsigned*)(SbT + zB0); p6b[s][1] = *(const unsigned*)(SbT + zB1);
            gA0 += str6A; gA1 += str6A; gB0 += str6B; gB1 += str6B;
            zA0 += ss4A; zA1 += ss4A; zB0 += ss4B; zB1 += ss4B;
        }
        int sh6 = 8 * lh;
        #pragma unroll 2
        for (int v = 0; v < 10; ++v) {
            int sl = v & 1;
            int sa0 = (int)((p6a[sl][0] >> sh6) & 255), sa1 = (int)((p6a[sl][1] >> sh6) & 255);
            int sb0 = (int)((p6b[sl][0] >> sh6) & 255), sb1 = (int)((p6b[sl][1] >> sh6) & 255);
            intx8 A0 = (intx8){ qa[sl][0][0].x, qa[sl][0][0].y, qa[sl][0][1].x, qa[sl][0][1].y, qa[sl][0][2].x, qa[sl][0][2].y, 0, 0 };
            intx8 A1 = (intx8){ qa[sl][1][0].x, qa[sl][1][0].y, qa[sl][1][1].x, qa[sl][1][1].y, qa[sl][1][2].x, qa[sl][1][2].y, 0, 0 };
            intx8 B0 = (intx8){ qb[sl][0][0].x, qb[sl][0][0].y, qb[sl][0][1].x, qb[sl][0][1].y, qb[sl][0][2].x, qb[sl][0][2].y, 0, 0 };
            intx8 B1 = (intx8){ qb[sl][1][0].x, qb[sl][1][0].y, qb[sl][1][1].x, qb[sl][1][1].y, qb[sl][1][2].x, qb[sl][1][2].y, 0, 0 };
            acc[0][0] = __builtin_amdgcn_mfma_scale_f32_32x32x64_f8f6f4(A0, B0, acc[0][0], 3, 3, 0, sa0, 0, sb0);
            acc[0][1] = __builtin_amdgcn_mfma_scale_f32_32x32x64_f8f6f4(A0, B1, acc[0][1], 3, 3, 0, sa0, 0, sb1);
            acc[1][0] = __builtin_amdgcn_mfma_scale_f32_32x32x64_f8f6f4(A1, B0, acc[1][0], 3, 3, 0, sa1, 0, sb0);
            acc[1][1] = __builtin_amdgcn_mfma_scale_f32_32x32x64_f8f6f4(A1, B1, acc[1][1], 3, 3, 0, sa1, 0, sb1);
            {   // prefetch v+2 into slot just consumed (v+2 <= 11: fully in-bounds)
                const unsigned char *a0 = A6 + gA0, *a1 = A6 + gA1, *b0 = B6 + gB0, *b1 = B6 + gB1;
                qa[sl][0][0] = *(const int2*)(a0); qa[sl][0][1] = *(const int2*)(a0 + 8); qa[sl][0][2] = *(const int2*)(a0 + 16);
                qa[sl][1][0] = *(const int2*)(a1); qa[sl][1][1] = *(const int2*)(a1 + 8); qa[sl][1][2] = *(const int2*)(a1 + 16);
                qb[sl][0][0] = *(const int2*)(b0); qb[sl][0][1] = *(const int2*)(b0 + 8); qb[sl][0][2] = *(const int2*)(b0 + 16);
                qb[sl][1][0] = *(const int2*)(b1); qb[sl][1][1] = *(const int2*)(b1 + 8); qb[sl][1][2] = *(const int2*)(b1 + 16);
                p6a[sl][0] = *(const unsigned*)(SaT + zA0); p6a[sl][1] = *(const unsigned*)(SaT + zA1);
                p6b[sl][0] = *(const unsigned*)(SbT + zB0); p6b[sl][1] = *(const unsigned*)(SbT + zB1);
                gA0 += str6A; gA1 += str6A; gB0 += str6B; gB1 += str6B;
                zA0 += ss4A; zA1 += ss4A; zB0 += ss4B; zB1 += ss4B;
            }
        }
        #pragma unroll
        for (int v = 10; v < 12; ++v) {   // peeled tail: consume-only (no stray scale reads)
            int sl = v & 1;
            int sa0 = (int)((p6a[sl][0] >> sh6) & 255), sa1 = (int)((p6a[sl][1] >> sh6) & 255);
            int sb0 = (int)((p6b[sl][0] >> sh6) & 255), sb1 = (int)((p6b[sl][1] >> sh6) & 255);
            intx8 A0 = (intx8){ qa[sl][0][0].x, qa[sl][0][0].y, qa[sl][0][1].x, qa[sl][0][1].y, qa[sl][0][2].x, qa[sl][0][2].y, 0, 0 };
            intx8 A1 = (intx8){ qa[sl][1][0].x, qa[sl][1][0].y, qa[sl][1][1].x, qa[sl][1][1].y, qa[sl][1][2].x, qa[sl][1][2].y, 0, 0 };
            intx8 B0 = (intx8){ qb[sl][0][0].x, qb[sl][0][0].y, qb[sl][0][1].x, qb[sl][0][1].y, qb[sl][0][2].x, qb[sl][0][2].y, 0, 0 };
            intx8 B1 = (intx8){ qb[sl][1][0].x, qb[sl][1][0].y, qb[sl][1][1].x, qb[sl][1][1].y, qb[sl][1][2].x, qb[sl][1][2].y, 0, 0 };
            acc[0][0] = __builtin_amdgcn_mfma_scale_f32_32x32x64_f8f6f4(A0, B0, acc[0][0], 3, 3, 0, sa0, 0, sb0);
            acc[0][1] = __builtin_amdgcn_mfma_scale_f32_32x32x64_f8f6f4(A0, B1, acc[0][1], 3, 3, 0, sa0, 0, sb1);
            acc[1][0] = __builtin_amdgcn_mfma_scale_f32_32x32x64_f8f6f4(A1, B0, acc[1][0], 3, 3, 0, sa1, 0, sb0);
            acc[1][1] = __builtin_amdgcn_mfma_scale_f32_32x32x64_f8f6f4(A1, B1, acc[1][1], 3, 3, 0, sa1, 0, sb1);
        }
    }

    // ================= fp8 as bf16: 16 steps of K=16, depth-2 pipeline =================
    {
        unsigned str8A = 32u * (unsigned)M, str8B = 32u * (unsigned)N;
        const unsigned char* A8b = (const unsigned char*)A8;
        const unsigned char* B8b = (const unsigned char*)B8;
        unsigned hA0 = ((unsigned)lh * M + (unsigned)rA[0]) * 16u;
        unsigned hA1 = ((unsigned)lh * M + (unsigned)rA[1]) * 16u;
        unsigned hB0 = ((unsigned)lh * N + (unsigned)cB[0]) * 16u;
        unsigned hB1 = ((unsigned)lh * N + (unsigned)cB[1]) * 16u;
        short8 ra[2][2], rb[2][2];
        #pragma unroll
        for (int s = 0; s < 2; ++s) {
            ra[s][0] = *(const short8*)(A8b + hA0); ra[s][1] = *(const short8*)(A8b + hA1);
            rb[s][0] = *(const short8*)(B8b + hB0); rb[s][1] = *(const short8*)(B8b + hB1);
            hA0 += str8A; hA1 += str8A; hB0 += str8B; hB1 += str8B;
        }
        #pragma unroll 2
        for (int q = 0; q < 16; ++q) {
            int sl = q & 1;
            acc[0][0] = __builtin_amdgcn_mfma_f32_32x32x16_bf16(ra[sl][0], rb[sl][0], acc[0][0], 0, 0, 0);
            acc[0][1] = __builtin_amdgcn_mfma_f32_32x32x16_bf16(ra[sl][0], rb[sl][1], acc[0][1], 0, 0, 0);
            acc[1][0] = __builtin_amdgcn_mfma_f32_32x32x16_bf16(ra[sl][1], rb[sl][0], acc[1][0], 0, 0, 0);
            acc[1][1] = __builtin_amdgcn_mfma_f32_32x32x16_bf16(ra[sl][1], rb[sl][1], acc[1][1], 0, 0, 0);
            // prefetch q+2 (tail strays stay inside B8->SaT / A8->B8 regions)
            ra[sl][0] = *(const short8*)(A8b + hA0); ra[sl][1] = *(const short8*)(A8b + hA1);
            rb[sl][0] = *(const short8*)(B8b + hB0); rb[sl][1] = *(const short8*)(B8b + hB1);
            hA0 += str8A; hA1 += str8A; hB0 += str8B; hB1 += str8B;
        }
    }

    // epilogue: 32x32 C/D layout col=lane&31, row=(r&3)+8*(r>>2)+4*lh (m74/m101-verified)
    #pragma unroll
    for (int i = 0; i < 2; i++)
        #pragma unroll
        for (int j = 0; j < 2; j++) {
            int col = bn * 128 + wn + j * 32 + lr;
            float bv = bias[col];
            #pragma unroll
            for (int r = 0; r < 16; r++) {
                int row = bm * 128 + wm + i * 32 + (r & 3) + 8 * (r >> 2) + 4 * lh;
                C[(size_t)row * N + col] = acc[i][j][r] + bv;
            }
        }
}

extern "C" void kernel_launch(void* const* d_in, const int* in_sizes, int n_in,
                              void* d_out, int out_size, void* d_ws, size_t ws_size,
                              hipStream_t stream) {
    const int* AN   = (const int*)d_in[0];
    const int* ASs  = (const int*)d_in[1];
    const int* AO   = (const int*)d_in[2];
    const int* SFAN = (const int*)d_in[3];
    const int* SFAS = (const int*)d_in[4];
    const int* SFAO = (const int*)d_in[5];
    const int* BN   = (const int*)d_in[6];
    const int* BS   = (const int*)d_in[7];
    const int* BO   = (const int*)d_in[8];
    const int* SFBN = (const int*)d_in[9];
    const int* SFBS = (const int*)d_in[10];
    const int* SFBO = (const int*)d_in[11];
    const float* bias = (const float*)d_in[12];

    int M = in_sizes[0] / 1536;
    int N = in_sizes[6] / 1536;

    unsigned char* ws = (unsigned char*)d_ws;
    size_t o = 0;
    unsigned char*  A4c = ws + o;                    o += (size_t)M * 1536;
    unsigned char*  B4c = ws + o;                    o += (size_t)N * 1536;
    unsigned char*  A6c = ws + o;                    o += (size_t)M * 576;
    unsigned char*  B6c = ws + o;                    o += (size_t)N * 576;
    unsigned short* A8d = (unsigned short*)(ws + o); o += (size_t)M * 512;
    unsigned short* B8d = (unsigned short*)(ws + o); o += (size_t)N * 512;
    unsigned char*  SaT = ws + o;                    o += (size_t)36 * M * 4;
    unsigned char*  SbT = ws + o;                    o += (size_t)36 * N * 4;

    int T = M * 116 + N * 116;
    pack_both<<<(T + 255) / 256, 256, 0, stream>>>(
        AN, ASs, AO, SFAN, SFAS, SFAO, A4c, A6c, A8d, SaT, M,
        BN, BS, BO, SFBN, SFBS, SFBO, B4c, B6c, B8d, SbT, N);

    dim3 grid(N / 128, M / 128);
    gemm_mx<<<grid, 256, 0, stream>>>(A4c, B4c, A6c, B6c, A8d, B8d,
                                      SaT, SbT, bias, (float*)d_out, M, N);
}